// Round 3
// baseline (235.995 us; speedup 1.0000x reference)
//
#include <hip/hip_runtime.h>

// Problem constants: B=4, C=256, H=W=64, KS=3, N=9
#define HW    4096
#define J_TOT 16384   // B*H*W
#define K_TOT 2304    // 9*256
#define C_CH  256
#define BROW  264     // Bs row pitch in u16 (+16B pad -> conflict-floor LDS access)

typedef unsigned short u16;
typedef unsigned int   u32;
typedef __attribute__((ext_vector_type(8))) short short8;   // 8 bf16 (4 VGPRs), MFMA A/B frag
typedef __attribute__((ext_vector_type(4))) float f32x4;    // MFMA C/D frag
typedef __attribute__((ext_vector_type(8))) unsigned short us8;

__device__ __forceinline__ float b2f(u16 u) { return __uint_as_float(((u32)u) << 16); }
__device__ __forceinline__ u16 f2b(float x) {             // RNE f32->bf16
  u32 u = __float_as_uint(x);
  u += 0x7FFFu + ((u >> 16) & 1u);
  return (u16)(u >> 16);
}

// ---------------------------------------------------------------------------
// Kernel 0: dtype detection (1 = bf16 inputs, 0 = f32 inputs).
// ---------------------------------------------------------------------------
__global__ void k_detect(const u16* __restrict__ f, int* __restrict__ flag) {
  __shared__ int sh[256];
  int t = threadIdx.x;
  int hits = 0;
  for (int i = t; i < 2048; i += 256) {
    u16 u = f[2 * i];
    int e = (u >> 7) & 0xFF;
    hits += (e >= 100 && e <= 141) ? 1 : 0;
  }
  sh[t] = hits;
  __syncthreads();
  if (t == 0) {
    int s = 0;
    for (int i = 0; i < 256; i++) s += sh[i];
    flag[0] = (s > 1024) ? 1 : 0;
  }
}

// ---------------------------------------------------------------------------
// Kernel 1: feature (b,c,h,w) -> channels-last bf16 ftr[b][hw][c]
// ---------------------------------------------------------------------------
__global__ void k_transpose(const void* __restrict__ featv, u16* __restrict__ ftr,
                            const int* __restrict__ flag) {
  __shared__ u16 tile[32][33];
  int isbf = *flag;
  int b = blockIdx.z;
  int hw0 = blockIdx.x << 5;
  int c0 = blockIdx.y << 5;
  int tx = threadIdx.x;  // 0..31 (hw on load, c on store)
  int ty = threadIdx.y;  // 0..7
  if (isbf) {
    const u16* f = (const u16*)featv;
#pragma unroll
    for (int i = 0; i < 4; i++) {
      int c = c0 + ty + i * 8;
      tile[ty + i * 8][tx] = f[(((size_t)(b * C_CH + c)) << 12) + hw0 + tx];
    }
  } else {
    const float* f = (const float*)featv;
#pragma unroll
    for (int i = 0; i < 4; i++) {
      int c = c0 + ty + i * 8;
      tile[ty + i * 8][tx] = f2b(f[(((size_t)(b * C_CH + c)) << 12) + hw0 + tx]);
    }
  }
  __syncthreads();
#pragma unroll
  for (int i = 0; i < 4; i++) {
    int hw = hw0 + ty + i * 8;
    ftr[(((size_t)(b * HW + hw)) << 8) + c0 + tx] = tile[tx][ty + i * 8];
  }
}

// ---------------------------------------------------------------------------
// Kernel 2: weight (o,c,3,3) -> Wr[o][k] bf16 with k = n*256 + c, n = i*3+j
// ---------------------------------------------------------------------------
__global__ void k_wconv(const void* __restrict__ wv, u16* __restrict__ Wr,
                        const int* __restrict__ flag) {
  int isbf = *flag;
  int idx = blockIdx.x * 256 + threadIdx.x;      // = o*2304 + n*256 + c
  if (idx >= C_CH * K_TOT) return;
  int c = idx & 255;
  int n = (idx >> 8) % 9;
  int o = idx / K_TOT;
  int src = (o * 256 + c) * 9 + n;
  if (isbf) Wr[idx] = ((const u16*)wv)[src];
  else      Wr[idx] = f2b(((const float*)wv)[src]);
}

// ---------------------------------------------------------------------------
// Kernel 3: FUSED deform-gather + GEMM + epilogue.
// Grid (256 j-blocks, 2 o-blocks) = 512 blocks (2/CU), 256 threads (4 waves).
// Block tile 64j x 128o; wave w owns o rows [w*32, w*32+32): 4x2 frags of
// 16x16x32 -> 8 MFMA per K-iter.
// Per n (9 phases): 4 threads/pixel recompute corner weights/indices
// (verified round-1/2 math), bilinear-interp the n-slice B panel
// (64px x 256c bf16) into padded LDS; 1 sync; 8 kc iterations reading
// A-fragments DIRECT from global (L2-resident Wr, no LDS, no syncs) and
// B-fragments from LDS; 1 sync. Epilogue: relu(relu(acc)+feature).
// ---------------------------------------------------------------------------
__global__ __launch_bounds__(256, 2) void k_fused(const u16* __restrict__ Wr,
                                                  const u16* __restrict__ ftr,
                                                  const void* __restrict__ offv,
                                                  const void* __restrict__ featv,
                                                  void* __restrict__ outv,
                                                  const int* __restrict__ flag) {
  __shared__ u16 Bs[64 * BROW];   // 33 KB
  int isbf = *flag;
  int jb = blockIdx.x << 6;
  int ob = blockIdx.y << 7;
  int b  = jb >> 12;              // whole block is in one batch (64 | 4096)
  int hw0 = jb & (HW - 1);
  int t = threadIdx.x;
  int wave = t >> 6, lane = t & 63;
  int lr = lane & 15, lk = lane >> 4;

  // B-producer role: 4 threads per pixel, each covers 64 channels
  int px = t >> 2, cq = t & 3;
  int phw = hw0 + px;
  int ph = phw >> 6, pw = phw & 63;

  // A fragment pointers (per-wave o rows, K-major; lanes cover dense 64B lines)
  const u16* a0 = Wr + (size_t)(ob + wave * 32 + lr) * K_TOT + lk * 8;
  const u16* a1 = a0 + (size_t)16 * K_TOT;

  f32x4 acc[2][4];
  f32x4 zero = {0.f, 0.f, 0.f, 0.f};
#pragma unroll
  for (int i = 0; i < 2; i++)
#pragma unroll
    for (int j = 0; j < 4; j++) acc[i][j] = zero;

  for (int n = 0; n < 9; n++) {
    // ---- corner math for this pixel (verbatim round-2, verified) ----
    size_t obi = (((size_t)(b * 18 + n)) << 12) + phw;
    float ox, oy;
    if (isbf) {
      const u16* po = (const u16*)offv;
      ox = b2f(po[obi]);
      oy = b2f(po[obi + (9u << 12)]);
    } else {
      const float* po = (const float*)offv;
      ox = po[obi];
      oy = po[obi + (9u << 12)];
    }
    int ki = n / 3, kj = n % 3;
    float sx = (float)(ph + ki) + ox;
    float sy = (float)(pw + kj) + oy;
    float fx = floorf(sx), fy = floorf(sy);
    float qltx = fminf(fmaxf(fx, 0.f), 65.f);
    float qlty = fminf(fmaxf(fy, 0.f), 65.f);
    float qrbx = fminf(fmaxf(fx + 1.f, 0.f), 65.f);
    float qrby = fminf(fmaxf(fy + 1.f, 0.f), 65.f);
    float pcx = fminf(fmaxf(sx, 0.f), 65.f);
    float pcy = fminf(fmaxf(sy, 0.f), 65.f);
    float dltx = 1.f + (qltx - pcx);
    float drbx = 1.f - (qrbx - pcx);
    float dlty = 1.f + (qlty - pcy);
    float drby = 1.f - (qrby - pcy);
    float g0 = dltx * dlty;   // (q_lt_x, q_lt_y)
    float g1 = drbx * drby;   // (q_rb_x, q_rb_y)
    float g2 = dltx * drby;   // (q_lt_x, q_rb_y)
    float g3 = drbx * dlty;   // (q_rb_x, q_lt_y)
    int x0 = (int)qltx, y0 = (int)qlty, x1 = (int)qrbx, y1 = (int)qrby;
    int v0 = (x0 >= 1 && x0 <= 64 && y0 >= 1 && y0 <= 64);
    int v1 = (x1 >= 1 && x1 <= 64 && y1 >= 1 && y1 <= 64);
    int v2 = (x0 >= 1 && x0 <= 64 && y1 >= 1 && y1 <= 64);
    int v3 = (x1 >= 1 && x1 <= 64 && y0 >= 1 && y0 <= 64);
    int base = b << 12;
    int i0 = v0 ? ((base + ((x0 - 1) << 6) + (y0 - 1)) << 8) : 0;
    int i1 = v1 ? ((base + ((x1 - 1) << 6) + (y1 - 1)) << 8) : 0;
    int i2 = v2 ? ((base + ((x0 - 1) << 6) + (y1 - 1)) << 8) : 0;
    int i3 = v3 ? ((base + ((x1 - 1) << 6) + (y0 - 1)) << 8) : 0;
    g0 = v0 ? g0 : 0.f;
    g1 = v1 ? g1 : 0.f;
    g2 = v2 ? g2 : 0.f;
    g3 = v3 ? g3 : 0.f;

    // ---- bilinear-interp this pixel's 64-channel slice into LDS ----
    const u16* f0 = ftr + i0;
    const u16* f1 = ftr + i1;
    const u16* f2 = ftr + i2;
    const u16* f3 = ftr + i3;
    u16* brow = &Bs[px * BROW] + cq * 64;
#pragma unroll
    for (int ch = 0; ch < 8; ch++) {
      int c = cq * 64 + ch * 8;
      us8 r0 = *(const us8*)(f0 + c);
      us8 r1 = *(const us8*)(f1 + c);
      us8 r2 = *(const us8*)(f2 + c);
      us8 r3 = *(const us8*)(f3 + c);
      us8 ov;
#pragma unroll
      for (int i = 0; i < 8; i++) {
        float v = g0 * b2f(r0[i]) + g1 * b2f(r1[i]) + g2 * b2f(r2[i]) + g3 * b2f(r3[i]);
        ov[i] = f2b(v);
      }
      *(us8*)(brow + ch * 8) = ov;
    }
    __syncthreads();

    // ---- 8 K-iterations, no internal barriers ----
    int k0 = n << 8;
#pragma unroll
    for (int kc = 0; kc < 8; kc++) {
      short8 af0 = *(const short8*)(a0 + k0 + kc * 32);
      short8 af1 = *(const short8*)(a1 + k0 + kc * 32);
      short8 bf[4];
#pragma unroll
      for (int ji = 0; ji < 4; ji++)
        bf[ji] = *(const short8*)(&Bs[(ji * 16 + lr) * BROW + kc * 32 + lk * 8]);
#pragma unroll
      for (int ji = 0; ji < 4; ji++) {
        acc[0][ji] = __builtin_amdgcn_mfma_f32_16x16x32_bf16(af0, bf[ji], acc[0][ji], 0, 0, 0);
        acc[1][ji] = __builtin_amdgcn_mfma_f32_16x16x32_bf16(af1, bf[ji], acc[1][ji], 0, 0, 0);
      }
    }
    __syncthreads();   // Bs reuse guard for next n
  }

  // ---- epilogue: D mapping col = lane&15 (j), row = (lane>>4)*4 + r (o) ----
#pragma unroll
  for (int oi = 0; oi < 2; oi++) {
#pragma unroll
    for (int ji = 0; ji < 4; ji++) {
      int j = jb + ji * 16 + lr;
      int hww = j & (HW - 1);
      int o0 = ob + wave * 32 + oi * 16 + lk * 4;
#pragma unroll
      for (int r = 0; r < 4; r++) {
        size_t oidx = (((size_t)(b * C_CH + o0 + r)) << 12) + hww;
        float v = acc[oi][ji][r];
        v = fmaxf(v, 0.f);
        float ft = isbf ? b2f(((const u16*)featv)[oidx]) : ((const float*)featv)[oidx];
        v = fmaxf(v + ft, 0.f);
        if (isbf) ((u16*)outv)[oidx] = f2b(v);
        else      ((float*)outv)[oidx] = v;
      }
    }
  }
}

extern "C" void kernel_launch(void* const* d_in, const int* in_sizes, int n_in,
                              void* d_out, int out_size, void* d_ws, size_t ws_size,
                              hipStream_t stream) {
  const void* feat = d_in[0];
  const void* offs = d_in[1];
  const void* wght = d_in[2];

  // workspace layout (256B-aligned sections), total ~9.6 MB
  const size_t off_flag = 0;
  const size_t off_wr   = 256;                          // bf16 Wr, 1.125 MB
  const size_t off_ftr  = off_wr + (size_t)1179648;     // bf16 channels-last feature, 8 MB
  const size_t need     = off_ftr + (size_t)8388608;
  if (ws_size < need) return;  // insufficient scratch; cannot run

  char* ws = (char*)d_ws;
  int* flag = (int*)(ws + off_flag);
  u16* Wr   = (u16*)(ws + off_wr);
  u16* ftr  = (u16*)(ws + off_ftr);

  k_detect<<<1, 256, 0, stream>>>((const u16*)feat, flag);
  k_transpose<<<dim3(128, 8, 4), dim3(32, 8), 0, stream>>>(feat, ftr, flag);
  k_wconv<<<K_TOT, 256, 0, stream>>>(wght, Wr, flag);
  k_fused<<<dim3(J_TOT / 64, 2), 256, 0, stream>>>(Wr, ftr, offs, feat, d_out, flag);
}

// Round 4
// 164.724 us; speedup vs baseline: 1.4327x; 1.4327x over previous
//
#include <hip/hip_runtime.h>

// Problem constants: B=4, C=256, H=W=64, KS=3, N=9
#define HW    4096
#define J_TOT 16384   // B*H*W
#define K_TOT 2304    // 9*256
#define C_CH  256

typedef unsigned short u16;
typedef unsigned int   u32;
typedef __attribute__((ext_vector_type(8))) short short8;   // 8 bf16 (4 VGPRs), MFMA A/B frag
typedef __attribute__((ext_vector_type(4))) float f32x4;    // MFMA C/D frag
typedef __attribute__((ext_vector_type(8))) unsigned short us8;

__device__ __forceinline__ float b2f(u16 u) { return __uint_as_float(((u32)u) << 16); }
__device__ __forceinline__ u16 f2b(float x) {             // RNE f32->bf16
  u32 u = __float_as_uint(x);
  u += 0x7FFFu + ((u >> 16) & 1u);
  return (u16)(u >> 16);
}

// ---------------------------------------------------------------------------
// Kernel 0: dtype detection (1 = bf16 inputs, 0 = f32 inputs).
// ---------------------------------------------------------------------------
__global__ void k_detect(const u16* __restrict__ f, int* __restrict__ flag) {
  __shared__ int sh[256];
  int t = threadIdx.x;
  int hits = 0;
  for (int i = t; i < 2048; i += 256) {
    u16 u = f[2 * i];
    int e = (u >> 7) & 0xFF;
    hits += (e >= 100 && e <= 141) ? 1 : 0;
  }
  sh[t] = hits;
  __syncthreads();
  if (t < 64) {
    int s = sh[t] + sh[t + 64] + sh[t + 128] + sh[t + 192];
#pragma unroll
    for (int off = 32; off > 0; off >>= 1) s += __shfl_down(s, off, 64);
    if (t == 0) flag[0] = (s > 1024) ? 1 : 0;
  }
}

// ---------------------------------------------------------------------------
// Kernel 1: feature (b,c,h,w) -> channels-last bf16 ftr[b][hw][c]
// ---------------------------------------------------------------------------
__global__ void k_transpose(const void* __restrict__ featv, u16* __restrict__ ftr,
                            const int* __restrict__ flag) {
  __shared__ u16 tile[32][33];
  int isbf = *flag;
  int b = blockIdx.z;
  int hw0 = blockIdx.x << 5;
  int c0 = blockIdx.y << 5;
  int tx = threadIdx.x;  // 0..31 (hw on load, c on store)
  int ty = threadIdx.y;  // 0..7
  if (isbf) {
    const u16* f = (const u16*)featv;
#pragma unroll
    for (int i = 0; i < 4; i++) {
      int c = c0 + ty + i * 8;
      tile[ty + i * 8][tx] = f[(((size_t)(b * C_CH + c)) << 12) + hw0 + tx];
    }
  } else {
    const float* f = (const float*)featv;
#pragma unroll
    for (int i = 0; i < 4; i++) {
      int c = c0 + ty + i * 8;
      tile[ty + i * 8][tx] = f2b(f[(((size_t)(b * C_CH + c)) << 12) + hw0 + tx]);
    }
  }
  __syncthreads();
#pragma unroll
  for (int i = 0; i < 4; i++) {
    int hw = hw0 + ty + i * 8;
    ftr[(((size_t)(b * HW + hw)) << 8) + c0 + tx] = tile[tx][ty + i * 8];
  }
}

// ---------------------------------------------------------------------------
// Kernel 2: weight (o,c,3,3) -> Wr[o][k] bf16 with k = n*256 + c, n = i*3+j
// ---------------------------------------------------------------------------
__global__ void k_wconv(const void* __restrict__ wv, u16* __restrict__ Wr,
                        const int* __restrict__ flag) {
  int isbf = *flag;
  int idx = blockIdx.x * 256 + threadIdx.x;      // = o*2304 + n*256 + c
  if (idx >= C_CH * K_TOT) return;
  int c = idx & 255;
  int n = (idx >> 8) % 9;
  int o = idx / K_TOT;
  int src = (o * 256 + c) * 9 + n;
  if (isbf) Wr[idx] = ((const u16*)wv)[src];
  else      Wr[idx] = f2b(((const float*)wv)[src]);
}

// ---------------------------------------------------------------------------
// Kernel 3: FUSED deform-gather + GEMM + epilogue, round-4 rework.
// Grid (256 j-blocks, 2 o-blocks) = 512 blocks (2/CU), 256 threads (4 waves).
// Block tile 64j x 128o; wave w owns o rows [w*32, w*32+32): 2x4 frags of
// 16x16x32 -> 8 MFMA per K-iter.
//
// Phase 0 (once): precompute corner idx/weights for all 576 (px,n) into LDS.
// Per n: producer (16 contiguous lanes per 256B segment -> coalesced corner
// reads) interps the 64px x 256c B panel into XOR-swizzled LDS (16B chunk
// c ^= row&7 -> conflict-floor ds_write_b128/ds_read_b128); barrier;
// consumer prefetches ALL 16 A-frags (64 VGPRs, 16 indep L2 loads in
// flight) then runs 8 kc x 8 MFMA; barrier.
// Epilogue: relu(relu(acc)+feature).
// ---------------------------------------------------------------------------
__global__ __launch_bounds__(256, 2) void k_fused(const u16* __restrict__ Wr,
                                                  const u16* __restrict__ ftr,
                                                  const void* __restrict__ offv,
                                                  const void* __restrict__ featv,
                                                  void* __restrict__ outv,
                                                  const int* __restrict__ flag) {
  __shared__ u16 Bs[64 * 256];        // 32 KB, row = 64 px, 32 chunks of 16B
  __shared__ int   cidx[9][64][4];    // 9 KB
  __shared__ float cgw[9][64][4];     // 9 KB
  int isbf = *flag;
  int jb = blockIdx.x << 6;
  int ob = blockIdx.y << 7;
  int b  = jb >> 12;                  // block = one h-row of one batch
  int hw0 = jb & (HW - 1);
  int t = threadIdx.x;
  int wave = t >> 6, lane = t & 63;
  int lr = lane & 15, lk = lane >> 4;

  // ---- Phase 0: corner math for all (px, n), 576 tasks ----
  for (int task = t; task < 576; task += 256) {
    int px = task & 63, n = task >> 6;
    int phw = hw0 + px;
    int ph = phw >> 6, pw = phw & 63;
    size_t obi = (((size_t)(b * 18 + n)) << 12) + phw;
    float ox, oy;
    if (isbf) {
      const u16* po = (const u16*)offv;
      ox = b2f(po[obi]);
      oy = b2f(po[obi + (9u << 12)]);
    } else {
      const float* po = (const float*)offv;
      ox = po[obi];
      oy = po[obi + (9u << 12)];
    }
    int ki = n / 3, kj = n % 3;
    float sx = (float)(ph + ki) + ox;
    float sy = (float)(pw + kj) + oy;
    float fx = floorf(sx), fy = floorf(sy);
    float qltx = fminf(fmaxf(fx, 0.f), 65.f);
    float qlty = fminf(fmaxf(fy, 0.f), 65.f);
    float qrbx = fminf(fmaxf(fx + 1.f, 0.f), 65.f);
    float qrby = fminf(fmaxf(fy + 1.f, 0.f), 65.f);
    float pcx = fminf(fmaxf(sx, 0.f), 65.f);
    float pcy = fminf(fmaxf(sy, 0.f), 65.f);
    float dltx = 1.f + (qltx - pcx);
    float drbx = 1.f - (qrbx - pcx);
    float dlty = 1.f + (qlty - pcy);
    float drby = 1.f - (qrby - pcy);
    float g0 = dltx * dlty;   // (q_lt_x, q_lt_y)
    float g1 = drbx * drby;   // (q_rb_x, q_rb_y)
    float g2 = dltx * drby;   // (q_lt_x, q_rb_y)
    float g3 = drbx * dlty;   // (q_rb_x, q_lt_y)
    int x0 = (int)qltx, y0 = (int)qlty, x1 = (int)qrbx, y1 = (int)qrby;
    int v0 = (x0 >= 1 && x0 <= 64 && y0 >= 1 && y0 <= 64);
    int v1 = (x1 >= 1 && x1 <= 64 && y1 >= 1 && y1 <= 64);
    int v2 = (x0 >= 1 && x0 <= 64 && y1 >= 1 && y1 <= 64);
    int v3 = (x1 >= 1 && x1 <= 64 && y0 >= 1 && y0 <= 64);
    int base = b << 12;
    cidx[n][px][0] = v0 ? ((base + ((x0 - 1) << 6) + (y0 - 1)) << 8) : 0;
    cidx[n][px][1] = v1 ? ((base + ((x1 - 1) << 6) + (y1 - 1)) << 8) : 0;
    cidx[n][px][2] = v2 ? ((base + ((x0 - 1) << 6) + (y1 - 1)) << 8) : 0;
    cidx[n][px][3] = v3 ? ((base + ((x1 - 1) << 6) + (y0 - 1)) << 8) : 0;
    cgw[n][px][0] = v0 ? g0 : 0.f;
    cgw[n][px][1] = v1 ? g1 : 0.f;
    cgw[n][px][2] = v2 ? g2 : 0.f;
    cgw[n][px][3] = v3 ? g3 : 0.f;
  }
  __syncthreads();

  // producer role: lane16 = channel segment, grp+16s = pixel
  int lane16 = t & 15, grp = t >> 4;

  // A base pointer (per-wave o rows; 16 rows x 64B lines, L2-resident)
  const u16* awr = Wr + (size_t)(ob + wave * 32 + lr) * K_TOT + lk * 8;

  f32x4 acc[2][4];
  f32x4 zero = {0.f, 0.f, 0.f, 0.f};
#pragma unroll
  for (int i = 0; i < 2; i++)
#pragma unroll
    for (int j = 0; j < 4; j++) acc[i][j] = zero;

  for (int n = 0; n < 9; n++) {
    // ---- producer: 4 px-subsets x 2 halves, coalesced 256B segments ----
#pragma unroll
    for (int s = 0; s < 4; s++) {
      int px = grp + s * 16;
      int i0 = cidx[n][px][0], i1 = cidx[n][px][1];
      int i2 = cidx[n][px][2], i3 = cidx[n][px][3];
      float g0 = cgw[n][px][0], g1 = cgw[n][px][1];
      float g2 = cgw[n][px][2], g3 = cgw[n][px][3];
#pragma unroll
      for (int half = 0; half < 2; half++) {
        int c16 = half * 16 + lane16;            // chunk index 0..31
        int ch = c16 * 8;                        // u16 offset in channel dim
        us8 r0 = *(const us8*)(ftr + i0 + ch);
        us8 r1 = *(const us8*)(ftr + i1 + ch);
        us8 r2 = *(const us8*)(ftr + i2 + ch);
        us8 r3 = *(const us8*)(ftr + i3 + ch);
        us8 ov;
#pragma unroll
        for (int i = 0; i < 8; i++) {
          float v = g0 * b2f(r0[i]) + g1 * b2f(r1[i]) + g2 * b2f(r2[i]) + g3 * b2f(r3[i]);
          ov[i] = f2b(v);
        }
        int cs = c16 ^ (px & 7);                 // XOR swizzle, 16B chunks
        *(us8*)(&Bs[px * 256 + cs * 8]) = ov;
      }
    }
    __syncthreads();

    // ---- consumer: prefetch all 16 A-frags, then 8 kc x 8 MFMA ----
    const u16* an = awr + (n << 8);
    short8 A0[8], A1[8];
#pragma unroll
    for (int kc = 0; kc < 8; kc++) {
      A0[kc] = *(const short8*)(an + kc * 32);
      A1[kc] = *(const short8*)(an + (size_t)16 * K_TOT + kc * 32);
    }
#pragma unroll
    for (int kc = 0; kc < 8; kc++) {
      short8 bf[4];
#pragma unroll
      for (int ji = 0; ji < 4; ji++) {
        int row = ji * 16 + lr;
        int cs = (kc * 4 + lk) ^ (lr & 7);
        bf[ji] = *(const short8*)(&Bs[row * 256 + cs * 8]);
      }
#pragma unroll
      for (int ji = 0; ji < 4; ji++) {
        acc[0][ji] = __builtin_amdgcn_mfma_f32_16x16x32_bf16(A0[kc], bf[ji], acc[0][ji], 0, 0, 0);
        acc[1][ji] = __builtin_amdgcn_mfma_f32_16x16x32_bf16(A1[kc], bf[ji], acc[1][ji], 0, 0, 0);
      }
    }
    __syncthreads();   // Bs reuse guard for next n
  }

  // ---- epilogue: D mapping col = lane&15 (j), row = (lane>>4)*4 + r (o) ----
#pragma unroll
  for (int oi = 0; oi < 2; oi++) {
#pragma unroll
    for (int ji = 0; ji < 4; ji++) {
      int j = jb + ji * 16 + lr;
      int hww = j & (HW - 1);
      int o0 = ob + wave * 32 + oi * 16 + lk * 4;
#pragma unroll
      for (int r = 0; r < 4; r++) {
        size_t oidx = (((size_t)(b * C_CH + o0 + r)) << 12) + hww;
        float v = acc[oi][ji][r];
        v = fmaxf(v, 0.f);
        float ft = isbf ? b2f(((const u16*)featv)[oidx]) : ((const float*)featv)[oidx];
        v = fmaxf(v + ft, 0.f);
        if (isbf) ((u16*)outv)[oidx] = f2b(v);
        else      ((float*)outv)[oidx] = v;
      }
    }
  }
}

extern "C" void kernel_launch(void* const* d_in, const int* in_sizes, int n_in,
                              void* d_out, int out_size, void* d_ws, size_t ws_size,
                              hipStream_t stream) {
  const void* feat = d_in[0];
  const void* offs = d_in[1];
  const void* wght = d_in[2];

  // workspace layout (256B-aligned sections), total ~9.6 MB
  const size_t off_flag = 0;
  const size_t off_wr   = 256;                          // bf16 Wr, 1.125 MB
  const size_t off_ftr  = off_wr + (size_t)1179648;     // bf16 channels-last feature, 8 MB
  const size_t need     = off_ftr + (size_t)8388608;
  if (ws_size < need) return;  // insufficient scratch; cannot run

  char* ws = (char*)d_ws;
  int* flag = (int*)(ws + off_flag);
  u16* Wr   = (u16*)(ws + off_wr);
  u16* ftr  = (u16*)(ws + off_ftr);

  k_detect<<<1, 256, 0, stream>>>((const u16*)feat, flag);
  k_transpose<<<dim3(128, 8, 4), dim3(32, 8), 0, stream>>>(feat, ftr, flag);
  k_wconv<<<K_TOT, 256, 0, stream>>>(wght, Wr, flag);
  k_fused<<<dim3(J_TOT / 64, 2), 256, 0, stream>>>(Wr, ftr, offs, feat, d_out, flag);
}

// Round 5
// 153.310 us; speedup vs baseline: 1.5393x; 1.0745x over previous
//
#include <hip/hip_runtime.h>

// Problem constants: B=4, C=256, H=W=64, KS=3, N=9
#define HW    4096
#define J_TOT 16384   // B*H*W
#define K_TOT 2304    // 9*256
#define C_CH  256

typedef unsigned short u16;
typedef unsigned int   u32;
typedef __attribute__((ext_vector_type(8))) short short8;   // 8 bf16 (4 VGPRs), MFMA A/B frag
typedef __attribute__((ext_vector_type(4))) float f32x4;    // MFMA C/D frag
typedef __attribute__((ext_vector_type(8))) unsigned short us8;

__device__ __forceinline__ float b2f(u16 u) { return __uint_as_float(((u32)u) << 16); }
__device__ __forceinline__ u16 f2b(float x) {             // RNE f32->bf16
  u32 u = __float_as_uint(x);
  u += 0x7FFFu + ((u >> 16) & 1u);
  return (u16)(u >> 16);
}

// ---------------------------------------------------------------------------
// Kernel 0: dtype detection (1 = bf16 inputs, 0 = f32 inputs).
// Round-4 WRITE_SIZE says f32, but keep the dual path (cheap, robust).
// ---------------------------------------------------------------------------
__global__ void k_detect(const u16* __restrict__ f, int* __restrict__ flag) {
  __shared__ int sh[256];
  int t = threadIdx.x;
  int hits = 0;
  for (int i = t; i < 2048; i += 256) {
    u16 u = f[2 * i];
    int e = (u >> 7) & 0xFF;
    hits += (e >= 100 && e <= 141) ? 1 : 0;
  }
  sh[t] = hits;
  __syncthreads();
  if (t < 64) {
    int s = sh[t] + sh[t + 64] + sh[t + 128] + sh[t + 192];
#pragma unroll
    for (int off = 32; off > 0; off >>= 1) s += __shfl_down(s, off, 64);
    if (t == 0) flag[0] = (s > 1024) ? 1 : 0;
  }
}

// ---------------------------------------------------------------------------
// Kernel 1: PREP (merged). Blocks 0..4095: feature (b,c,h,w) -> channels-last
// bf16 ftr[b][hw][c]. Blocks 4096..6399: weight (o,c,3,3) -> Wr[o][n*256+c].
// ---------------------------------------------------------------------------
__global__ __launch_bounds__(256) void k_prep(const void* __restrict__ featv,
                                              const void* __restrict__ wv,
                                              u16* __restrict__ ftr,
                                              u16* __restrict__ Wr,
                                              const int* __restrict__ flag) {
  int isbf = *flag;
  int bi = blockIdx.x;
  int t = threadIdx.x;
  if (bi < 4096) {
    __shared__ u16 tile[32][33];
    int b = bi >> 10;
    int y = (bi >> 7) & 7;
    int x = bi & 127;
    int hw0 = x << 5;
    int c0 = y << 5;
    int tx = t & 31, ty = t >> 5;
    if (isbf) {
      const u16* f = (const u16*)featv;
#pragma unroll
      for (int i = 0; i < 4; i++) {
        int c = c0 + ty + i * 8;
        tile[ty + i * 8][tx] = f[(((size_t)(b * C_CH + c)) << 12) + hw0 + tx];
      }
    } else {
      const float* f = (const float*)featv;
#pragma unroll
      for (int i = 0; i < 4; i++) {
        int c = c0 + ty + i * 8;
        tile[ty + i * 8][tx] = f2b(f[(((size_t)(b * C_CH + c)) << 12) + hw0 + tx]);
      }
    }
    __syncthreads();
#pragma unroll
    for (int i = 0; i < 4; i++) {
      int hw = hw0 + ty + i * 8;
      ftr[(((size_t)(b * HW + hw)) << 8) + c0 + tx] = tile[tx][ty + i * 8];
    }
  } else {
    int idx = (bi - 4096) * 256 + t;             // = o*2304 + n*256 + c
    if (idx < C_CH * K_TOT) {
      int c = idx & 255;
      int n = (idx >> 8) % 9;
      int o = idx / K_TOT;
      int src = (o * 256 + c) * 9 + n;
      if (isbf) Wr[idx] = ((const u16*)wv)[src];
      else      Wr[idx] = f2b(((const float*)wv)[src]);
    }
  }
}

// ---------------------------------------------------------------------------
// Kernel 2: FUSED deform-gather + GEMM + epilogue, producer/consumer waves.
// Grid 256 blocks (one per 64-px chunk; all 256 o per block), 512 threads:
// waves 0-3 consumers (wave tile 64j x 64o, 4x4 frags 16x16x32), waves 4-7
// producers. Double-buffered 32KB B panels in LDS; ONE barrier per n-phase:
// producers interp panel n while consumers MFMA panel n-1.
// Phase 0 precomputes all 576 (px,n) corner idx/weights into LDS.
// A (weights) read direct from L2-resident Wr, prefetched 16 frags deep.
// Epilogue: relu(relu(acc)+feature).
// ---------------------------------------------------------------------------
__global__ __launch_bounds__(512, 2) void k_fused(const u16* __restrict__ Wr,
                                                  const u16* __restrict__ ftr,
                                                  const void* __restrict__ offv,
                                                  const void* __restrict__ featv,
                                                  void* __restrict__ outv,
                                                  const int* __restrict__ flag) {
  __shared__ u16 Bs[2][64 * 256];     // 2 x 32 KB, row = px, 32 chunks of 16B
  __shared__ int   cidx[9][64][4];    // 9 KB
  __shared__ float cgw[9][64][4];     // 9 KB
  int isbf = *flag;
  int jb = blockIdx.x << 6;
  int b  = jb >> 12;                  // block = one h-row of one batch
  int hw0 = jb & (HW - 1);
  int t = threadIdx.x;
  int wave = t >> 6, lane = t & 63;
  int lr = lane & 15, lk = lane >> 4;

  // ---- Phase 0: corner math for all (px, n), 576 tasks over 512 threads ----
  for (int task = t; task < 576; task += 512) {
    int px = task & 63, n = task >> 6;
    int phw = hw0 + px;
    int ph = phw >> 6, pw = phw & 63;
    size_t obi = (((size_t)(b * 18 + n)) << 12) + phw;
    float ox, oy;
    if (isbf) {
      const u16* po = (const u16*)offv;
      ox = b2f(po[obi]);
      oy = b2f(po[obi + (9u << 12)]);
    } else {
      const float* po = (const float*)offv;
      ox = po[obi];
      oy = po[obi + (9u << 12)];
    }
    int ki = n / 3, kj = n % 3;
    float sx = (float)(ph + ki) + ox;
    float sy = (float)(pw + kj) + oy;
    float fx = floorf(sx), fy = floorf(sy);
    float qltx = fminf(fmaxf(fx, 0.f), 65.f);
    float qlty = fminf(fmaxf(fy, 0.f), 65.f);
    float qrbx = fminf(fmaxf(fx + 1.f, 0.f), 65.f);
    float qrby = fminf(fmaxf(fy + 1.f, 0.f), 65.f);
    float pcx = fminf(fmaxf(sx, 0.f), 65.f);
    float pcy = fminf(fmaxf(sy, 0.f), 65.f);
    float dltx = 1.f + (qltx - pcx);
    float drbx = 1.f - (qrbx - pcx);
    float dlty = 1.f + (qlty - pcy);
    float drby = 1.f - (qrby - pcy);
    float g0 = dltx * dlty;   // (q_lt_x, q_lt_y)
    float g1 = drbx * drby;   // (q_rb_x, q_rb_y)
    float g2 = dltx * drby;   // (q_lt_x, q_rb_y)
    float g3 = drbx * dlty;   // (q_rb_x, q_lt_y)
    int x0 = (int)qltx, y0 = (int)qlty, x1 = (int)qrbx, y1 = (int)qrby;
    int v0 = (x0 >= 1 && x0 <= 64 && y0 >= 1 && y0 <= 64);
    int v1 = (x1 >= 1 && x1 <= 64 && y1 >= 1 && y1 <= 64);
    int v2 = (x0 >= 1 && x0 <= 64 && y1 >= 1 && y1 <= 64);
    int v3 = (x1 >= 1 && x1 <= 64 && y0 >= 1 && y0 <= 64);
    int base = b << 12;
    cidx[n][px][0] = v0 ? ((base + ((x0 - 1) << 6) + (y0 - 1)) << 8) : 0;
    cidx[n][px][1] = v1 ? ((base + ((x1 - 1) << 6) + (y1 - 1)) << 8) : 0;
    cidx[n][px][2] = v2 ? ((base + ((x0 - 1) << 6) + (y1 - 1)) << 8) : 0;
    cidx[n][px][3] = v3 ? ((base + ((x1 - 1) << 6) + (y0 - 1)) << 8) : 0;
    cgw[n][px][0] = v0 ? g0 : 0.f;
    cgw[n][px][1] = v1 ? g1 : 0.f;
    cgw[n][px][2] = v2 ? g2 : 0.f;
    cgw[n][px][3] = v3 ? g3 : 0.f;
  }

  f32x4 acc[4][4];   // consumer: [oi][ji]
  f32x4 zero = {0.f, 0.f, 0.f, 0.f};
#pragma unroll
  for (int i = 0; i < 4; i++)
#pragma unroll
    for (int j = 0; j < 4; j++) acc[i][j] = zero;

  // producer identity (waves 4-7): lane16 = channel chunk, grp = px subset
  int pt = t - 256;
  int lane16 = pt & 15, grp = pt >> 4;
  // consumer A base (rows o = wave*64 + oi*16 + lr, K-major)
  const u16* aw = Wr + (size_t)(wave * 64 + lr) * K_TOT + lk * 8;

  for (int it = 0; it < 10; it++) {
    __syncthreads();
    if (wave >= 4) {
      // ---------------- producer: interp panel `it` into Bs[it&1] ----------
      if (it < 9) {
        int n = it;
        u16* dstp = Bs[it & 1];
#pragma unroll
        for (int s = 0; s < 4; s++) {
          int px = grp + s * 16;
          int i0 = cidx[n][px][0], i1 = cidx[n][px][1];
          int i2 = cidx[n][px][2], i3 = cidx[n][px][3];
          float g0 = cgw[n][px][0], g1 = cgw[n][px][1];
          float g2 = cgw[n][px][2], g3 = cgw[n][px][3];
#pragma unroll
          for (int half = 0; half < 2; half++) {
            int c16 = half * 16 + lane16;        // chunk index 0..31
            int ch = c16 * 8;
            us8 r0 = *(const us8*)(ftr + i0 + ch);
            us8 r1 = *(const us8*)(ftr + i1 + ch);
            us8 r2 = *(const us8*)(ftr + i2 + ch);
            us8 r3 = *(const us8*)(ftr + i3 + ch);
            us8 ov;
#pragma unroll
            for (int i = 0; i < 8; i++) {
              float v = g0 * b2f(r0[i]) + g1 * b2f(r1[i]) + g2 * b2f(r2[i]) + g3 * b2f(r3[i]);
              ov[i] = f2b(v);
            }
            int cs = c16 ^ (px & 7);             // XOR swizzle, 16B chunks
            *(us8*)(&dstp[px * 256 + cs * 8]) = ov;
          }
        }
      }
    } else {
      // ---------------- consumer: MFMA panel `it-1` from Bs[(it-1)&1] ------
      if (it > 0) {
        int m = it - 1;
        const u16* srcp = Bs[m & 1];
        const u16* an = aw + (m << 8);
#pragma unroll
        for (int kh = 0; kh < 2; kh++) {
          short8 A[4][4];
#pragma unroll
          for (int oi = 0; oi < 4; oi++)
#pragma unroll
            for (int k2 = 0; k2 < 4; k2++)
              A[oi][k2] = *(const short8*)(an + (size_t)oi * 16 * K_TOT + (kh * 4 + k2) * 32);
#pragma unroll
          for (int k2 = 0; k2 < 4; k2++) {
            int kc = kh * 4 + k2;
            short8 bf[4];
#pragma unroll
            for (int ji = 0; ji < 4; ji++) {
              int row = ji * 16 + lr;
              int cs = (kc * 4 + lk) ^ (lr & 7);
              bf[ji] = *(const short8*)(&srcp[row * 256 + cs * 8]);
            }
#pragma unroll
            for (int oi = 0; oi < 4; oi++)
#pragma unroll
              for (int ji = 0; ji < 4; ji++)
                acc[oi][ji] = __builtin_amdgcn_mfma_f32_16x16x32_bf16(A[oi][k2], bf[ji], acc[oi][ji], 0, 0, 0);
          }
        }
      }
    }
  }

  // ---- epilogue (consumers): D col = lane&15 (j), row = (lane>>4)*4+r (o) --
  if (wave < 4) {
#pragma unroll
    for (int oi = 0; oi < 4; oi++) {
#pragma unroll
      for (int ji = 0; ji < 4; ji++) {
        int j = jb + ji * 16 + lr;
        int hww = j & (HW - 1);
        int o0 = wave * 64 + oi * 16 + lk * 4;
#pragma unroll
        for (int r = 0; r < 4; r++) {
          size_t oidx = (((size_t)(b * C_CH + o0 + r)) << 12) + hww;
          float v = acc[oi][ji][r];
          v = fmaxf(v, 0.f);
          float ft = isbf ? b2f(((const u16*)featv)[oidx]) : ((const float*)featv)[oidx];
          v = fmaxf(v + ft, 0.f);
          if (isbf) ((u16*)outv)[oidx] = f2b(v);
          else      ((float*)outv)[oidx] = v;
        }
      }
    }
  }
}

extern "C" void kernel_launch(void* const* d_in, const int* in_sizes, int n_in,
                              void* d_out, int out_size, void* d_ws, size_t ws_size,
                              hipStream_t stream) {
  const void* feat = d_in[0];
  const void* offs = d_in[1];
  const void* wght = d_in[2];

  // workspace layout (256B-aligned sections), total ~9.6 MB
  const size_t off_flag = 0;
  const size_t off_wr   = 256;                          // bf16 Wr, 1.125 MB
  const size_t off_ftr  = off_wr + (size_t)1179648;     // bf16 channels-last feature, 8 MB
  const size_t need     = off_ftr + (size_t)8388608;
  if (ws_size < need) return;  // insufficient scratch; cannot run

  char* ws = (char*)d_ws;
  int* flag = (int*)(ws + off_flag);
  u16* Wr   = (u16*)(ws + off_wr);
  u16* ftr  = (u16*)(ws + off_ftr);

  k_detect<<<1, 256, 0, stream>>>((const u16*)feat, flag);
  k_prep<<<4096 + 2304, 256, 0, stream>>>(feat, wght, ftr, Wr, flag);
  k_fused<<<J_TOT / 64, 512, 0, stream>>>(Wr, ftr, offs, feat, d_out, flag);
}